// Round 13
// baseline (368.637 us; speedup 1.0000x reference)
//
#include <hip/hip_runtime.h>
#include <math.h>

#define NN   10000
#define EE   200000
#define RR   400000
#define FIN  128
#define FOUT 64
#define AJP  10048           // adjE padded row stride (bf16), 16B-aligned

#define HASH_BITS 20
#define HSIZE (1u << HASH_BITS)
#define HMASK (HSIZE - 1u)
#define ROWCAP 256           // per-row edge slots (Poisson(40): P(>256)~0)

#define NKB 314              // k-blocks of 32 covering 10048
#define L2E 1.442695041f
#define CHALF 0.7213475204f  // 0.5*log2(e)

typedef __bf16 bf16x8 __attribute__((ext_vector_type(8)));
typedef __bf16 bf16x4 __attribute__((ext_vector_type(4)));
typedef float  f32x4  __attribute__((ext_vector_type(4)));

// ---- workspace layout (units of 4 bytes) ----
#define O_SUMS   0
#define O_CNTS   (O_SUMS + EE)
#define O_S      (O_CNTS + EE)             // f32[NN], exact row sums
#define O_ROWCNT (O_S + NN)                // int[NN]
#define O_HKEY   (O_ROWCNT + NN)
#define O_HPRIO  (O_HKEY + HSIZE)
#define O_SEQTP  (O_HPRIO + HSIZE)         // packed bf16 [NKB][5][64][8]
#define SEQTP_WORDS (NKB * 5 * 512 / 2)
#define ZERO_WORDS (O_SEQTP + SEQTP_WORDS) // 2,919,072 (div by 4)
#define O_ADJE   ZERO_WORDS                // bf16[NN][AJP]
#define O_NUMP   (O_ADJE + NN * AJP / 2)   // f32[8][NN][64]
#define O_PAIRS  (O_NUMP + 8 * NN * FOUT)  // uint2[NN][ROWCAP]

// ---------------- wide zero fill ----------------
__global__ __launch_bounds__(256) void k_zero(f32x4* __restrict__ p, int n4) {
    int gid = blockIdx.x * 256 + threadIdx.x;
    if (gid < n4) p[gid] = (f32x4){0.f, 0.f, 0.f, 0.f};
}

// -------- seq_fts = x @ W^T, emitted as MFMA-fragment-packed bf16 ----------
// packed(kb, n, lane, slot) = seq[col = n*16+(lane&15)][k = kb*32+(lane>>4)*8+slot]
__global__ __launch_bounds__(256) void k_seqfts(const float* __restrict__ x,
                                                const float* __restrict__ W,
                                                __bf16* __restrict__ seqTp) {
    __shared__ float Wt[FIN][FOUT + 1];
    __shared__ float xs[FIN][16 + 1];
    int t = threadIdx.x;
    for (int e = t; e < FOUT * FIN; e += 256) {
        int c = e >> 7, k = e & 127;
        Wt[k][c] = W[e];
    }
    int row0 = blockIdx.x * 16;
    for (int e = t; e < 16 * FIN; e += 256) {
        int r = e >> 7, k = e & 127;
        int gr = row0 + r;
        xs[k][r] = (gr < NN) ? x[(size_t)gr * FIN + k] : 0.f;
    }
    __syncthreads();
    int col = t & 63;
    int rg  = t >> 6;
    float acc[4] = {0.f, 0.f, 0.f, 0.f};
    for (int k = 0; k < FIN; ++k) {
        float w = Wt[k][col];
        #pragma unroll
        for (int i = 0; i < 4; ++i) acc[i] += w * xs[k][rg * 4 + i];
    }
    #pragma unroll
    for (int i = 0; i < 4; ++i) {
        int gr = row0 + rg * 4 + i;          // K index, < NN
        int kb = gr >> 5, g = (gr >> 3) & 3, slot = gr & 7;
        seqTp[((size_t)kb * 5 + (col >> 4)) * 512 + ((col & 15) + g * 16) * 8 + slot]
            = (__bf16)acc[i];
    }
}

// ---------------- helpers ----------------
__device__ __forceinline__ unsigned hash_cell(unsigned cell) {
    return (cell * 2654435761u) >> (32 - HASH_BITS);
}
__device__ __forceinline__ void entry_ij(const int* ep, int e, int& i, int& j, int& k) {
    k = (e < EE) ? e : e - EE;
    int a = ep[2 * k], b = ep[2 * k + 1];
    if (e < EE) { i = a; j = b; } else { i = b; j = a; }
}

// ------- pass 1 (pure streaming): adjE = bf16(exp(adj+0.5)) + row sums S
//         || rel segsum || hash build.  No barriers; 8-10 loads in flight. ---
#define CRB 16250                          // 13*1250: 8 conv + 5 rel per 13
#define HASHB2 1563
#define GRID_CR (CRB + HASHB2)

__global__ __launch_bounds__(256) void k_convrel(const float* __restrict__ adj,
                                                 const float* __restrict__ rel,
                                                 const float* __restrict__ wrel,
                                                 const int* __restrict__ rseg,
                                                 const int* __restrict__ ep,
                                                 __bf16* __restrict__ adjE,
                                                 float* __restrict__ S,
                                                 float* __restrict__ sums,
                                                 float* __restrict__ cnts,
                                                 unsigned* __restrict__ hkey,
                                                 unsigned* __restrict__ hprio) {
    int t = threadIdx.x, bid = blockIdx.x;

    if (bid >= CRB) {
        // ---- hash-build role ----
        int e = (bid - CRB) * 256 + t;
        if (e >= 2 * EE) return;
        int i, j, k;
        entry_ij(ep, e, i, j, k);
        unsigned cell = (unsigned)i * NN + (unsigned)j;
        unsigned keyv = cell + 1u;
        unsigned h = hash_cell(cell);
        while (true) {
            unsigned old = atomicCAS(&hkey[h], 0u, keyv);
            if (old == 0u || old == keyv) break;
            h = (h + 1u) & HMASK;
        }
        atomicMax(&hprio[h], (unsigned)(e + 1));
        return;
    }

    int m = bid % 13;
    int grp = bid / 13;
    int l = t & 63;

    if (m >= 8) {
        // ---- rel role: 64 rows per block, batch-issue 8 row loads ----
        int relb = grp * 5 + (m - 8);      // [0, 6250); 6250*64 == RR exact
        int lane = l & 31;
        f32x4 wv = *(const f32x4*)(wrel + lane * 4);
        int rbase = relb * 64 + (t >> 5);  // 8 row-slots per pass
        f32x4 pv[8];
        #pragma unroll
        for (int pass = 0; pass < 8; ++pass)
            pv[pass] = *(const f32x4*)(rel + (size_t)(rbase + pass * 8) * FIN + lane * 4);
        #pragma unroll
        for (int pass = 0; pass < 8; ++pass) {
            f32x4 v = pv[pass];
            float s = v.x * wv.x + v.y * wv.y + v.z * wv.z + v.w * wv.w;
            s += __shfl_xor(s, 1, 64);
            s += __shfl_xor(s, 2, 64);
            s += __shfl_xor(s, 4, 64);
            s += __shfl_xor(s, 8, 64);
            s += __shfl_xor(s, 16, 64);
            if (lane == 0) {
                int row = rbase + pass * 8;
                int seg = rseg[row];
                atomicAdd(&sums[seg], s);
                atomicAdd(&cnts[seg], 1.0f);
            }
        }
        return;
    }

    // ---- conv role: one row per block, 4 waves x 2500-col segments ----
    int row = grp * 8 + m;                 // [0, 10000)
    int w = t >> 6;
    const float* ap = adj + (size_t)row * NN + w * 2500;
    __bf16* op = adjE + (size_t)row * AJP + w * 2500;

    f32x4 pv[10];
    #pragma unroll
    for (int i = 0; i < 10; ++i) {
        int off = i * 256 + l * 4;
        pv[i] = (off < 2500) ? *(const f32x4*)(ap + off) : (f32x4){0.f, 0.f, 0.f, 0.f};
    }
    float psum = 0.f;
    #pragma unroll
    for (int i = 0; i < 10; ++i) {
        int off = i * 256 + l * 4;
        if (off < 2500) {
            f32x4 v = pv[i];
            float e0 = exp2f(fmaf(v.x, L2E, CHALF));
            float e1 = exp2f(fmaf(v.y, L2E, CHALF));
            float e2 = exp2f(fmaf(v.z, L2E, CHALF));
            float e3 = exp2f(fmaf(v.w, L2E, CHALF));
            psum += (e0 + e1) + (e2 + e3);
            bf16x4 q = { (__bf16)e0, (__bf16)e1, (__bf16)e2, (__bf16)e3 };
            *(bf16x4*)(op + off) = q;
        } else if (w == 3 && (7500 + off) < AJP) {
            // zero the row pad [10000, 10048) so MFMA A-pad is clean
            bf16x4 z = { (__bf16)0.f, (__bf16)0.f, (__bf16)0.f, (__bf16)0.f };
            *(bf16x4*)(op + off) = z;
        }
    }
    psum += __shfl_xor(psum, 1, 64);
    psum += __shfl_xor(psum, 2, 64);
    psum += __shfl_xor(psum, 4, 64);
    psum += __shfl_xor(psum, 8, 64);
    psum += __shfl_xor(psum, 16, 64);
    psum += __shfl_xor(psum, 32, 64);
    if (l == 0) atomicAdd(&S[row], psum);
}

// ------- pass 2: Num = adjE @ seqTp (MFMA, R6 structure, bf16 input)
//         || scatB role (winner check + bucket push) as odd-block filler ----
#define MAINB2 1256                        // 157 rowchunks x 8 ksplit
#define SCATB2 1563
#define GRID_MS (2512 + (SCATB2 - 1256))   // 2819

__global__ __launch_bounds__(256) void k_mainscat(const __bf16* __restrict__ adjE,
                                                  const __bf16* __restrict__ seqTp,
                                                  const int* __restrict__ ep,
                                                  const float* __restrict__ sums,
                                                  const float* __restrict__ cnts,
                                                  const unsigned* __restrict__ hkey,
                                                  const unsigned* __restrict__ hprio,
                                                  const float* __restrict__ adj,
                                                  int* __restrict__ rowcnt,
                                                  uint2* __restrict__ pairs,
                                                  float* __restrict__ Nump) {
    __shared__ __bf16 As[2][64][72];       // 18432 B, stride 144B: 2-way-free banks
    int t = threadIdx.x, bid = blockIdx.x;

    if (bid >= 2512 || (bid & 1)) {
        // ---- scatB role ----
        int sid = (bid < 2512) ? (bid >> 1) : (1256 + bid - 2512);
        int e = sid * 256 + t;
        if (e >= 2 * EE) return;
        int i, j, k;
        entry_ij(ep, e, i, j, k);
        unsigned cell = (unsigned)i * NN + (unsigned)j;
        unsigned keyv = cell + 1u;
        unsigned h = hash_cell(cell);
        while (hkey[h] != keyv) h = (h + 1u) & HMASK;
        if (hprio[h] == (unsigned)(e + 1)) {   // last-write-wins winner
            float v   = sums[k] / fmaxf(cnts[k], 1.0f);
            float sg  = 1.f / (1.f + __expf(-v));
            float aij = adj[(size_t)i * NN + j];
            float dw  = __expf(aij + sg) - __expf(aij + 0.5f);
            if (dw != 0.f) {
                int pos = atomicAdd(&rowcnt[i], 1);
                if (pos < ROWCAP)
                    pairs[(size_t)i * ROWCAP + pos] =
                        make_uint2((unsigned)j, __float_as_uint(dw));
            }
        }
        return;
    }

    // ---- main role: 64x64 tile, K-split 8, dbuf LDS, B-frags from L2 ----
    int mi   = bid >> 1;                   // [0, 1256)
    int rowc = mi % 157;
    int ks   = mi / 157;
    int row0 = rowc * 64;
    int c0 = ks * 20, c1 = min(157, c0 + 20);
    int w = t >> 6, l = t & 63;
    int lr = l & 15, lk = l >> 4;
    int sr2 = t >> 3;                      // staging row 0..31
    int sc8 = (t & 7) * 8;                 // staging col (bf16x8)

    f32x4 acc[4];
    #pragma unroll
    for (int n = 0; n < 4; ++n) acc[n] = (f32x4){0.f, 0.f, 0.f, 0.f};

    bf16x8 pvA[2], pvB[2];
    const bf16x8 zf = {};

#define LOADA(PV, CH)                                                          \
    {                                                                          \
        int k0_ = (CH) * 64;                                                   \
        int r1 = row0 + sr2, r2 = row0 + 32 + sr2;                             \
        PV[0] = (r1 < NN) ? *(const bf16x8*)(adjE + (size_t)r1 * AJP + k0_ + sc8) : zf; \
        PV[1] = (r2 < NN) ? *(const bf16x8*)(adjE + (size_t)r2 * AJP + k0_ + sc8) : zf; \
    }

#define BODY(PV, CH, P_)                                                       \
    {                                                                          \
        *(bf16x8*)&As[P_][sr2][sc8]      = PV[0];                              \
        *(bf16x8*)&As[P_][32 + sr2][sc8] = PV[1];                              \
        const __bf16* bp = seqTp + (size_t)(CH) * 2 * 5 * 512 + l * 8;         \
        bf16x8 b0 = *(const bf16x8*)(bp);                                      \
        bf16x8 b1 = *(const bf16x8*)(bp + 512);                                \
        bf16x8 b2 = *(const bf16x8*)(bp + 1024);                               \
        bf16x8 b3 = *(const bf16x8*)(bp + 1536);                               \
        bf16x8 d0 = *(const bf16x8*)(bp + 2560);                               \
        bf16x8 d1 = *(const bf16x8*)(bp + 3072);                               \
        bf16x8 d2 = *(const bf16x8*)(bp + 3584);                               \
        bf16x8 d3 = *(const bf16x8*)(bp + 4096);                               \
        __syncthreads();                                                       \
        bf16x8 a0 = *(const bf16x8*)&As[P_][w * 16 + lr][lk * 8];              \
        acc[0] = __builtin_amdgcn_mfma_f32_16x16x32_bf16(a0, b0, acc[0], 0, 0, 0); \
        acc[1] = __builtin_amdgcn_mfma_f32_16x16x32_bf16(a0, b1, acc[1], 0, 0, 0); \
        acc[2] = __builtin_amdgcn_mfma_f32_16x16x32_bf16(a0, b2, acc[2], 0, 0, 0); \
        acc[3] = __builtin_amdgcn_mfma_f32_16x16x32_bf16(a0, b3, acc[3], 0, 0, 0); \
        bf16x8 a1 = *(const bf16x8*)&As[P_][w * 16 + lr][32 + lk * 8];         \
        acc[0] = __builtin_amdgcn_mfma_f32_16x16x32_bf16(a1, d0, acc[0], 0, 0, 0); \
        acc[1] = __builtin_amdgcn_mfma_f32_16x16x32_bf16(a1, d1, acc[1], 0, 0, 0); \
        acc[2] = __builtin_amdgcn_mfma_f32_16x16x32_bf16(a1, d2, acc[2], 0, 0, 0); \
        acc[3] = __builtin_amdgcn_mfma_f32_16x16x32_bf16(a1, d3, acc[3], 0, 0, 0); \
    }

    LOADA(pvA, c0);
    int ch = c0, p = 0;
    while (true) {
        if (ch + 1 < c1) LOADA(pvB, ch + 1);
        BODY(pvA, ch, p);
        p ^= 1; ++ch;
        if (ch >= c1) break;
        if (ch + 1 < c1) LOADA(pvA, ch + 1);
        BODY(pvB, ch, p);
        p ^= 1; ++ch;
        if (ch >= c1) break;
    }
#undef LOADA
#undef BODY

    // C/D layout: col = lane&15, row = (lane>>4)*4 + reg
    float* nout = Nump + (size_t)ks * NN * FOUT;
    #pragma unroll
    for (int n = 0; n < 4; ++n) {
        #pragma unroll
        for (int r = 0; r < 4; ++r) {
            int grow = row0 + w * 16 + lk * 4 + r;
            if (grow < NN)
                nout[(size_t)grow * FOUT + n * 16 + lr] = acc[n][r];
        }
    }
}

// ------- rowupd: one wave per row: sum partials + edge corr + elu -> out ----
__global__ __launch_bounds__(256) void k_rowupd(const float* __restrict__ Nump,
                                                const float* __restrict__ S,
                                                const int* __restrict__ rowcnt,
                                                const uint2* __restrict__ pairs,
                                                const __bf16* __restrict__ seqTp,
                                                const float* __restrict__ bias,
                                                float* __restrict__ out) {
    int t = threadIdx.x;
    int i = blockIdx.x * 4 + (t >> 6);
    if (i >= NN) return;
    int c = t & 63;
    float acc = 0.f;
    #pragma unroll
    for (int ks = 0; ks < 8; ++ks)
        acc += Nump[(size_t)ks * NN * FOUT + (size_t)i * FOUT + c];
    float sb = S[i];
    int cnt = min(rowcnt[i], ROWCAP);
    float sdw = 0.f;
    const uint2* pr = pairs + (size_t)i * ROWCAP;
    for (int e = 0; e < cnt; ++e) {
        uint2 pk = pr[e];                  // wave-uniform broadcast load
        float d  = __uint_as_float(pk.y);
        unsigned j = pk.x;
        float sj = (float)seqTp[((size_t)(j >> 5) * 5 + (c >> 4)) * 512
                                + ((c & 15) + ((j >> 3) & 3) * 16) * 8 + (j & 7)];
        acc += d * sj;
        sdw += d;
    }
    float v = acc / (sb + sdw) + bias[c];
    out[(size_t)i * FOUT + c] = (v > 0.f) ? v : expm1f(v);
}

extern "C" void kernel_launch(void* const* d_in, const int* in_sizes, int n_in,
                              void* d_out, int out_size, void* d_ws, size_t ws_size,
                              hipStream_t stream) {
    const float* x    = (const float*)d_in[0];
    const float* rel  = (const float*)d_in[1];
    const float* adj  = (const float*)d_in[2];
    const int*   ep   = (const int*)d_in[3];
    const int*   rseg = (const int*)d_in[4];
    const float* W    = (const float*)d_in[5];
    const float* wrel = (const float*)d_in[6];
    const float* bias = (const float*)d_in[7];
    float* out = (float*)d_out;

    float* ws = (float*)d_ws;
    float*    sums   = ws + O_SUMS;
    float*    cnts   = ws + O_CNTS;
    float*    S      = ws + O_S;
    int*      rowcnt = (int*)(ws + O_ROWCNT);
    unsigned* hkey   = (unsigned*)(ws + O_HKEY);
    unsigned* hprio  = (unsigned*)(ws + O_HPRIO);
    __bf16*   seqTp  = (__bf16*)(ws + O_SEQTP);
    __bf16*   adjE   = (__bf16*)(ws + O_ADJE);
    float*    Nump   = ws + O_NUMP;
    uint2*    pairs  = (uint2*)(ws + O_PAIRS);

    int n4 = ZERO_WORDS / 4;
    k_zero<<<(n4 + 255) / 256, 256, 0, stream>>>((f32x4*)d_ws, n4);
    k_seqfts<<<NN / 16, 256, 0, stream>>>(x, W, seqTp);
    k_convrel<<<GRID_CR, 256, 0, stream>>>(adj, rel, wrel, rseg, ep,
                                           adjE, S, sums, cnts, hkey, hprio);
    k_mainscat<<<GRID_MS, 256, 0, stream>>>(adjE, seqTp, ep, sums, cnts,
                                            hkey, hprio, adj, rowcnt, pairs, Nump);
    k_rowupd<<<(NN + 3) / 4, 256, 0, stream>>>(Nump, S, rowcnt, pairs,
                                               seqTp, bias, out);
}

// Round 14
// 264.632 us; speedup vs baseline: 1.3930x; 1.3930x over previous
//
#include <hip/hip_runtime.h>
#include <math.h>

#define NN   10000
#define EE   200000
#define RR   400000
#define FIN  128
#define FOUT 64
#define NK   10048           // 157*64, K padded for seqT

#define HASH_BITS 20
#define HSIZE (1u << HASH_BITS)
#define HMASK (HSIZE - 1u)
#define ROWCAP 256           // per-row edge slots (Binomial(400K,1e-4): P(>256)~0)

typedef __bf16 bf16x8 __attribute__((ext_vector_type(8)));
typedef __bf16 bf16x4 __attribute__((ext_vector_type(4)));
typedef float  f32x4  __attribute__((ext_vector_type(4)));

// ---- workspace layout (units of 4 bytes) ----
#define O_SUMS   0
#define O_CNTS   (O_SUMS + EE)
#define O_ROWCNT (O_CNTS + EE)             // int[NN]
#define O_HKEY   (O_ROWCNT + NN)
#define O_HPRIO  (O_HKEY + HSIZE)
#define O_SEQT   (O_HPRIO + HSIZE)         // bf16[64][NK] (pad cols must be 0)
#define ZERO_WORDS (O_SEQT + (FOUT * NK) / 2)   // div by 4
#define O_SEQ    ZERO_WORDS                // f32[NN][64]
#define O_NUMP   (O_SEQ + NN * FOUT)       // f32[8][NN][64] partials
#define O_SP     (O_NUMP + 8 * NN * FOUT)  // f32[8][NN]
#define O_PAIRS  (O_SP + 8 * NN)           // uint2[NN][ROWCAP]

// ---------------- wide zero fill ----------------
__global__ __launch_bounds__(256) void k_zero(f32x4* __restrict__ p, int n4) {
    int gid = blockIdx.x * 256 + threadIdx.x;
    if (gid < n4) p[gid] = (f32x4){0.f, 0.f, 0.f, 0.f};
}

// ---------------- seq_fts = x @ W^T  (also emits bf16 transposed copy) ----
__global__ __launch_bounds__(256) void k_seqfts(const float* __restrict__ x,
                                                const float* __restrict__ W,
                                                float* __restrict__ seq,
                                                __bf16* __restrict__ seqT) {
    __shared__ float Wt[FIN][FOUT + 1];
    __shared__ float xs[FIN][16 + 1];
    int t = threadIdx.x;
    for (int e = t; e < FOUT * FIN; e += 256) {
        int c = e >> 7, k = e & 127;
        Wt[k][c] = W[e];
    }
    int row0 = blockIdx.x * 16;
    for (int e = t; e < 16 * FIN; e += 256) {
        int r = e >> 7, k = e & 127;
        int gr = row0 + r;
        xs[k][r] = (gr < NN) ? x[(size_t)gr * FIN + k] : 0.f;
    }
    __syncthreads();
    int col = t & 63;
    int rg  = t >> 6;
    float acc[4] = {0.f, 0.f, 0.f, 0.f};
    for (int k = 0; k < FIN; ++k) {
        float w = Wt[k][col];
        #pragma unroll
        for (int i = 0; i < 4; ++i) acc[i] += w * xs[k][rg * 4 + i];
    }
    #pragma unroll
    for (int i = 0; i < 4; ++i) {
        int gr = row0 + rg * 4 + i;
        if (gr < NN) {
            seq[(size_t)gr * FOUT + col] = acc[i];
            seqT[(size_t)col * NK + gr] = (__bf16)acc[i];
        }
    }
}

// ---------------- helpers ----------------
__device__ __forceinline__ unsigned hash_cell(unsigned cell) {
    return (cell * 2654435761u) >> (32 - HASH_BITS);
}
__device__ __forceinline__ void entry_ij(const int* ep, int e, int& i, int& j, int& k) {
    k = (e < EE) ? e : e - EE;
    int a = ep[2 * k], b = ep[2 * k + 1];
    if (e < EE) { i = a; j = b; } else { i = b; j = a; }
}

// ------- merged: main matmul (partials)  ||  rel segsum  ||  hash build -----
#define BM 64
#define BK 64
#define KSPLIT 8
#define NCHUNK 157
#define CPK ((NCHUNK + KSPLIT - 1) / KSPLIT)   // 20
#define MAINB (NCHUNK * KSPLIT)                // 1256
#define ILV   11                               // 1 main : 10 rel
#define MRB   (ILV * MAINB)                    // 13816 (12560 rel slots)
#define SCATAB ((2 * EE + 255) / 256)          // 1563
#define GRID_MR (MRB + SCATAB)
#define LDAP (BK + 8)

__global__ __launch_bounds__(256) void k_mainrel(const float* __restrict__ adj,
                                                 const __bf16* __restrict__ seqT,
                                                 const float* __restrict__ rel,
                                                 const float* __restrict__ wrel,
                                                 const int* __restrict__ rseg,
                                                 const int* __restrict__ ep,
                                                 float* __restrict__ sums,
                                                 float* __restrict__ cnts,
                                                 unsigned* __restrict__ hkey,
                                                 unsigned* __restrict__ hprio,
                                                 float* __restrict__ Nump,
                                                 float* __restrict__ Sp) {
    __shared__ __bf16 As[2][BM][LDAP];
    __shared__ __bf16 Bs[2][FOUT][LDAP];
    int t   = threadIdx.x;
    int bid = blockIdx.x;

    if (bid >= MRB) {
        // ---- hash-build role (runs in tail; must finish before k_scatB) ----
        int e = (bid - MRB) * 256 + t;
        if (e >= 2 * EE) return;
        int i, j, k;
        entry_ij(ep, e, i, j, k);
        unsigned cell = (unsigned)i * NN + (unsigned)j;
        unsigned keyv = cell + 1u;
        unsigned h = hash_cell(cell);
        while (true) {
            unsigned old = atomicCAS(&hkey[h], 0u, keyv);
            if (old == 0u || old == keyv) break;
            h = (h + 1u) & HMASK;
        }
        atomicMax(&hprio[h], (unsigned)(e + 1));
        return;
    }

    if (bid % ILV) {
        // ---- rel role: 32 rows per block, 32-lane group per row ----
        int relb = bid - bid / ILV - 1;        // [0, 12560)
        int lane = t & 31;
        f32x4 w = *(const f32x4*)(wrel + lane * 4);
        #pragma unroll
        for (int it = 0; it < 4; ++it) {
            int row = relb * 32 + it * 8 + (t >> 5);
            if (row < RR) {
                f32x4 v = __builtin_nontemporal_load(
                    (const f32x4*)(rel + (size_t)row * FIN + lane * 4));
                float s = v.x * w.x + v.y * w.y + v.z * w.z + v.w * w.w;
                #pragma unroll
                for (int off = 16; off >= 1; off >>= 1) s += __shfl_xor(s, off, 64);
                if (lane == 0) {
                    int seg = rseg[row];
                    atomicAdd(&sums[seg], s);
                    atomicAdd(&cnts[seg], 1.0f);
                }
            }
        }
        return;
    }

    // ---- main role ----
    int mi   = bid / ILV;          // [0, 1256)
    int rowc = mi % NCHUNK;
    int ks   = mi / NCHUNK;
    int row0 = rowc * BM;
    int c0   = ks * CPK;
    int c1   = min(NCHUNK, c0 + CPK);
    int w  = t >> 6, l = t & 63;
    int lr = l & 15, lk = l >> 4;
    int sr = t >> 4;               // A-stage row within 16-row strip
    int sk = (t & 15) * 4;         // A-stage col (float4)
    int bc = t >> 3;               // B-stage col 0..31 (+32)
    int bk = (t & 7) * 8;          // B-stage k (bf16x8)

    f32x4 acc[4];
    #pragma unroll
    for (int n = 0; n < 4; ++n) acc[n] = (f32x4){0.f, 0.f, 0.f, 0.f};
    float rs[4] = {0.f, 0.f, 0.f, 0.f};

    f32x4  pva[4];
    bf16x8 pvb0, pvb1;

#define LOADC(CH)                                                              \
    {                                                                          \
        int k0_ = (CH) * BK;                                                   \
        _Pragma("unroll")                                                      \
        for (int e2 = 0; e2 < 4; ++e2) {                                       \
            int gr = row0 + sr + e2 * 16;                                      \
            int gk = k0_ + sk;                                                 \
            bool ok = (gr < NN) && (gk < NN);                                  \
            pva[e2] = ok ? __builtin_nontemporal_load(                         \
                               (const f32x4*)(adj + (size_t)gr * NN + gk))     \
                         : (f32x4){0.f, 0.f, 0.f, 0.f};                        \
        }                                                                      \
        pvb0 = *(const bf16x8*)(seqT + (size_t)bc * NK + k0_ + bk);            \
        pvb1 = *(const bf16x8*)(seqT + (size_t)(bc + 32) * NK + k0_ + bk);     \
    }

    LOADC(c0);
    int p = 0;
    for (int ch = c0; ch < c1; ++ch) {
        // drain prefetch regs into LDS[p] (exp fused for A, row-sums in regs)
        *(bf16x8*)&Bs[p][bc][bk]      = pvb0;
        *(bf16x8*)&Bs[p][bc + 32][bk] = pvb1;
        bool okk = (ch * BK + sk < NN);
        #pragma unroll
        for (int e2 = 0; e2 < 4; ++e2) {
            bool ok = okk && (row0 + sr + e2 * 16 < NN);
            float w0 = ok ? __expf(pva[e2].x + 0.5f) : 0.f;
            float w1 = ok ? __expf(pva[e2].y + 0.5f) : 0.f;
            float w2 = ok ? __expf(pva[e2].z + 0.5f) : 0.f;
            float w3 = ok ? __expf(pva[e2].w + 0.5f) : 0.f;
            bf16x4 bv = { (__bf16)w0, (__bf16)w1, (__bf16)w2, (__bf16)w3 };
            *(bf16x4*)&As[p][sr + e2 * 16][sk] = bv;
            rs[e2] += w0 + w1 + w2 + w3;
        }
        if (ch + 1 < c1) LOADC(ch + 1);        // issue next-chunk loads
        __syncthreads();                        // LDS[p] ready (1 barrier/chunk)
        #pragma unroll
        for (int kss = 0; kss < 2; ++kss) {
            bf16x8 a = *(const bf16x8*)&As[p][w * 16 + lr][kss * 32 + lk * 8];
            #pragma unroll
            for (int n = 0; n < 4; ++n) {
                bf16x8 b = *(const bf16x8*)&Bs[p][n * 16 + lr][kss * 32 + lk * 8];
                acc[n] = __builtin_amdgcn_mfma_f32_16x16x32_bf16(a, b, acc[n], 0, 0, 0);
            }
        }
        p ^= 1;
    }
#undef LOADC

    // row-sum partials: reduce across the 16 lanes sharing a row, plain store
    #pragma unroll
    for (int e = 0; e < 4; ++e) {
        float pp = rs[e];
        pp += __shfl_xor(pp, 1, 64);
        pp += __shfl_xor(pp, 2, 64);
        pp += __shfl_xor(pp, 4, 64);
        pp += __shfl_xor(pp, 8, 64);
        int r = e * 16 + sr;
        if ((t & 15) == 0 && row0 + r < NN)
            Sp[(size_t)ks * NN + row0 + r] = pp;
    }
    // C/D layout: col = lane&15, row = (lane>>4)*4 + reg ; plain stores
    #pragma unroll
    for (int n = 0; n < 4; ++n) {
        #pragma unroll
        for (int r = 0; r < 4; ++r) {
            int grow = row0 + w * 16 + lk * 4 + r;
            if (grow < NN)
                Nump[(size_t)ks * NN * FOUT + (size_t)grow * FOUT + n * 16 + lr]
                    = acc[n][r];
        }
    }
}

// ------- scatB: winner check + dw compute + push (j,dw) into row bucket -----
__global__ __launch_bounds__(256) void k_scatB(const int* __restrict__ ep,
                                               const float* __restrict__ sums,
                                               const float* __restrict__ cnts,
                                               const unsigned* __restrict__ hkey,
                                               const unsigned* __restrict__ hprio,
                                               const float* __restrict__ adj,
                                               int* __restrict__ rowcnt,
                                               uint2* __restrict__ pairs) {
    int e = blockIdx.x * 256 + threadIdx.x;
    if (e >= 2 * EE) return;
    int i, j, k;
    entry_ij(ep, e, i, j, k);
    unsigned cell = (unsigned)i * NN + (unsigned)j;
    unsigned keyv = cell + 1u;
    unsigned h = hash_cell(cell);
    while (hkey[h] != keyv) h = (h + 1u) & HMASK;
    if (hprio[h] == (unsigned)(e + 1)) {   // last-write-wins winner
        float v   = sums[k] / fmaxf(cnts[k], 1.0f);
        float sg  = 1.f / (1.f + __expf(-v));
        float aij = adj[(size_t)i * NN + j];
        float dw  = __expf(aij + sg) - __expf(aij + 0.5f);
        if (dw != 0.f) {
            int pos = atomicAdd(&rowcnt[i], 1);
            if (pos < ROWCAP)
                pairs[(size_t)i * ROWCAP + pos] =
                    make_uint2((unsigned)j, __float_as_uint(dw));
        }
    }
}

// ------- rowupd: one wave per row: sum partials + edge corr + elu -> out ----
__global__ __launch_bounds__(256) void k_rowupd(const float* __restrict__ Nump,
                                                const float* __restrict__ Sp,
                                                const int* __restrict__ rowcnt,
                                                const uint2* __restrict__ pairs,
                                                const float* __restrict__ seq,
                                                const float* __restrict__ bias,
                                                float* __restrict__ out) {
    int t = threadIdx.x;
    int i = blockIdx.x * 4 + (t >> 6);
    if (i >= NN) return;
    int c = t & 63;
    float acc = 0.f, sb = 0.f;
    #pragma unroll
    for (int ks = 0; ks < 8; ++ks) {
        acc += Nump[(size_t)ks * NN * FOUT + (size_t)i * FOUT + c];
        sb  += Sp[(size_t)ks * NN + i];
    }
    int cnt = min(rowcnt[i], ROWCAP);
    float sdw = 0.f;
    const uint2* pr = pairs + (size_t)i * ROWCAP;
    #pragma unroll 4
    for (int e = 0; e < cnt; ++e) {
        uint2 pk = pr[e];                      // wave-uniform broadcast load
        float d  = __uint_as_float(pk.y);
        acc += d * seq[(size_t)pk.x * FOUT + c];
        sdw += d;
    }
    float v = acc / (sb + sdw) + bias[c];
    out[(size_t)i * FOUT + c] = (v > 0.f) ? v : expm1f(v);
}

extern "C" void kernel_launch(void* const* d_in, const int* in_sizes, int n_in,
                              void* d_out, int out_size, void* d_ws, size_t ws_size,
                              hipStream_t stream) {
    const float* x    = (const float*)d_in[0];
    const float* rel  = (const float*)d_in[1];
    const float* adj  = (const float*)d_in[2];
    const int*   ep   = (const int*)d_in[3];
    const int*   rseg = (const int*)d_in[4];
    const float* W    = (const float*)d_in[5];
    const float* wrel = (const float*)d_in[6];
    const float* bias = (const float*)d_in[7];
    float* out = (float*)d_out;

    float* ws = (float*)d_ws;
    float*    sums   = ws + O_SUMS;
    float*    cnts   = ws + O_CNTS;
    int*      rowcnt = (int*)(ws + O_ROWCNT);
    unsigned* hkey   = (unsigned*)(ws + O_HKEY);
    unsigned* hprio  = (unsigned*)(ws + O_HPRIO);
    __bf16*   seqT   = (__bf16*)(ws + O_SEQT);
    float*    seq    = ws + O_SEQ;
    float*    Nump   = ws + O_NUMP;
    float*    Sp     = ws + O_SP;
    uint2*    pairs  = (uint2*)(ws + O_PAIRS);

    int n4 = ZERO_WORDS / 4;
    k_zero<<<(n4 + 255) / 256, 256, 0, stream>>>((f32x4*)d_ws, n4);
    k_seqfts<<<NN / 16, 256, 0, stream>>>(x, W, seq, seqT);
    k_mainrel<<<GRID_MR, 256, 0, stream>>>(adj, seqT, rel, wrel, rseg, ep,
                                           sums, cnts, hkey, hprio, Nump, Sp);
    k_scatB<<<SCATAB, 256, 0, stream>>>(ep, sums, cnts, hkey, hprio, adj,
                                        rowcnt, pairs);
    k_rowupd<<<(NN + 3) / 4, 256, 0, stream>>>(Nump, Sp, rowcnt, pairs,
                                               seq, bias, out);
}

// Round 16
// 264.407 us; speedup vs baseline: 1.3942x; 1.0009x over previous
//
#include <hip/hip_runtime.h>
#include <math.h>

#define NN   10000
#define EE   200000
#define RR   400000
#define FIN  128
#define FOUT 64
#define NK   10048           // 157*64, K padded for seqT

#define HASH_BITS 20
#define HSIZE (1u << HASH_BITS)
#define HMASK (HSIZE - 1u)
#define ROWCAP 256           // per-row edge slots (Binomial(400K,1e-4): P(>256)~0)

typedef __bf16 bf16x8 __attribute__((ext_vector_type(8)));
typedef __bf16 bf16x4 __attribute__((ext_vector_type(4)));
typedef float  f32x4  __attribute__((ext_vector_type(4)));

// ---- workspace layout (units of 4 bytes) ----
#define O_SUMS   0
#define O_CNTS   (O_SUMS + EE)
#define O_ROWCNT (O_CNTS + EE)             // int[NN]
#define O_HKEY   (O_ROWCNT + NN)
#define O_HPRIO  (O_HKEY + HSIZE)
#define O_SEQT   (O_HPRIO + HSIZE)         // bf16[64][NK] (pad cols must be 0)
#define ZERO_WORDS (O_SEQT + (FOUT * NK) / 2)   // div by 4
#define O_SEQ    ZERO_WORDS                // f32[NN][64]
#define O_NUMP   (O_SEQ + NN * FOUT)       // f32[8][NN][64] partials
#define O_SP     (O_NUMP + 8 * NN * FOUT)  // f32[8][NN]
#define O_PAIRS  (O_SP + 8 * NN)           // uint2[NN][ROWCAP]

// ---------------- wide zero fill ----------------
__global__ __launch_bounds__(256) void k_zero(f32x4* __restrict__ p, int n4) {
    int gid = blockIdx.x * 256 + threadIdx.x;
    if (gid < n4) p[gid] = (f32x4){0.f, 0.f, 0.f, 0.f};
}

// ---------------- seq_fts = x @ W^T  (also emits bf16 transposed copy) ----
__global__ __launch_bounds__(256) void k_seqfts(const float* __restrict__ x,
                                                const float* __restrict__ W,
                                                float* __restrict__ seq,
                                                __bf16* __restrict__ seqT) {
    __shared__ float Wt[FIN][FOUT + 1];
    __shared__ float xs[FIN][16 + 1];
    int t = threadIdx.x;
    for (int e = t; e < FOUT * FIN; e += 256) {
        int c = e >> 7, k = e & 127;
        Wt[k][c] = W[e];
    }
    int row0 = blockIdx.x * 16;
    for (int e = t; e < 16 * FIN; e += 256) {
        int r = e >> 7, k = e & 127;
        int gr = row0 + r;
        xs[k][r] = (gr < NN) ? x[(size_t)gr * FIN + k] : 0.f;
    }
    __syncthreads();
    int col = t & 63;
    int rg  = t >> 6;
    float acc[4] = {0.f, 0.f, 0.f, 0.f};
    for (int k = 0; k < FIN; ++k) {
        float w = Wt[k][col];
        #pragma unroll
        for (int i = 0; i < 4; ++i) acc[i] += w * xs[k][rg * 4 + i];
    }
    #pragma unroll
    for (int i = 0; i < 4; ++i) {
        int gr = row0 + rg * 4 + i;
        if (gr < NN) {
            seq[(size_t)gr * FOUT + col] = acc[i];
            seqT[(size_t)col * NK + gr] = (__bf16)acc[i];
        }
    }
}

// ---------------- helpers ----------------
__device__ __forceinline__ unsigned hash_cell(unsigned cell) {
    return (cell * 2654435761u) >> (32 - HASH_BITS);
}
__device__ __forceinline__ void entry_ij(const int* ep, int e, int& i, int& j, int& k) {
    k = (e < EE) ? e : e - EE;
    int a = ep[2 * k], b = ep[2 * k + 1];
    if (e < EE) { i = a; j = b; } else { i = b; j = a; }
}

// ------- merged: main matmul (partials)  ||  rel segsum  ||  hash build -----
#define BM 64
#define BK 64
#define KSPLIT 8
#define NCHUNK 157
#define CPK ((NCHUNK + KSPLIT - 1) / KSPLIT)   // 20
#define MAINB (NCHUNK * KSPLIT)                // 1256
#define ILV   11                               // 1 main : 10 rel
#define MRB   (ILV * MAINB)                    // 13816 (12560 rel slots)
#define SCATAB ((2 * EE + 255) / 256)          // 1563
#define GRID_MR (MRB + SCATAB)
#define LDAP (BK + 8)

__global__ __launch_bounds__(256) void k_mainrel(const float* __restrict__ adj,
                                                 const __bf16* __restrict__ seqT,
                                                 const float* __restrict__ rel,
                                                 const float* __restrict__ wrel,
                                                 const int* __restrict__ rseg,
                                                 const int* __restrict__ ep,
                                                 float* __restrict__ sums,
                                                 float* __restrict__ cnts,
                                                 unsigned* __restrict__ hkey,
                                                 unsigned* __restrict__ hprio,
                                                 float* __restrict__ Nump,
                                                 float* __restrict__ Sp) {
    __shared__ __bf16 As[2][BM][LDAP];
    __shared__ __bf16 Bs[2][FOUT][LDAP];
    int t   = threadIdx.x;
    int bid = blockIdx.x;

    if (bid >= MRB) {
        // ---- hash-build role (runs in tail; must finish before k_scatB) ----
        int e = (bid - MRB) * 256 + t;
        if (e >= 2 * EE) return;
        int i, j, k;
        entry_ij(ep, e, i, j, k);
        unsigned cell = (unsigned)i * NN + (unsigned)j;
        unsigned keyv = cell + 1u;
        unsigned h = hash_cell(cell);
        while (true) {
            unsigned old = atomicCAS(&hkey[h], 0u, keyv);
            if (old == 0u || old == keyv) break;
            h = (h + 1u) & HMASK;
        }
        atomicMax(&hprio[h], (unsigned)(e + 1));
        return;
    }

    if (bid % ILV) {
        // ---- rel role: 32 rows per block, 32-lane group per row ----
        int relb = bid - bid / ILV - 1;        // [0, 12560)
        int lane = t & 31;
        f32x4 w = *(const f32x4*)(wrel + lane * 4);
        #pragma unroll
        for (int it = 0; it < 4; ++it) {
            int row = relb * 32 + it * 8 + (t >> 5);
            if (row < RR) {
                f32x4 v = __builtin_nontemporal_load(
                    (const f32x4*)(rel + (size_t)row * FIN + lane * 4));
                float s = v.x * w.x + v.y * w.y + v.z * w.z + v.w * w.w;
                #pragma unroll
                for (int off = 16; off >= 1; off >>= 1) s += __shfl_xor(s, off, 64);
                if (lane == 0) {
                    int seg = rseg[row];
                    atomicAdd(&sums[seg], s);
                    atomicAdd(&cnts[seg], 1.0f);
                }
            }
        }
        return;
    }

    // ---- main role ----
    int mi   = bid / ILV;          // [0, 1256)
    int rowc = mi % NCHUNK;
    int ks   = mi / NCHUNK;
    int row0 = rowc * BM;
    int c0   = ks * CPK;
    int c1   = min(NCHUNK, c0 + CPK);
    int w  = t >> 6, l = t & 63;
    int lr = l & 15, lk = l >> 4;
    int sr = t >> 4;               // A-stage row within 16-row strip
    int sk = (t & 15) * 4;         // A-stage col (float4)
    int bc = t >> 3;               // B-stage col 0..31 (+32)
    int bk = (t & 7) * 8;          // B-stage k (bf16x8)

    f32x4 acc[4];
    #pragma unroll
    for (int n = 0; n < 4; ++n) acc[n] = (f32x4){0.f, 0.f, 0.f, 0.f};
    float rs[4] = {0.f, 0.f, 0.f, 0.f};

    f32x4  pva[4];
    bf16x8 pvb0, pvb1;

#define LOADC(CH)                                                              \
    {                                                                          \
        int k0_ = (CH) * BK;                                                   \
        _Pragma("unroll")                                                      \
        for (int e2 = 0; e2 < 4; ++e2) {                                       \
            int gr = row0 + sr + e2 * 16;                                      \
            int gk = k0_ + sk;                                                 \
            bool ok = (gr < NN) && (gk < NN);                                  \
            pva[e2] = ok ? __builtin_nontemporal_load(                         \
                               (const f32x4*)(adj + (size_t)gr * NN + gk))     \
                         : (f32x4){0.f, 0.f, 0.f, 0.f};                        \
        }                                                                      \
        pvb0 = *(const bf16x8*)(seqT + (size_t)bc * NK + k0_ + bk);            \
        pvb1 = *(const bf16x8*)(seqT + (size_t)(bc + 32) * NK + k0_ + bk);     \
    }

    LOADC(c0);
    int p = 0;
    for (int ch = c0; ch < c1; ++ch) {
        // drain prefetch regs into LDS[p] (exp fused for A, row-sums in regs)
        *(bf16x8*)&Bs[p][bc][bk]      = pvb0;
        *(bf16x8*)&Bs[p][bc + 32][bk] = pvb1;
        bool okk = (ch * BK + sk < NN);
        #pragma unroll
        for (int e2 = 0; e2 < 4; ++e2) {
            bool ok = okk && (row0 + sr + e2 * 16 < NN);
            float w0 = ok ? __expf(pva[e2].x + 0.5f) : 0.f;
            float w1 = ok ? __expf(pva[e2].y + 0.5f) : 0.f;
            float w2 = ok ? __expf(pva[e2].z + 0.5f) : 0.f;
            float w3 = ok ? __expf(pva[e2].w + 0.5f) : 0.f;
            bf16x4 bv = { (__bf16)w0, (__bf16)w1, (__bf16)w2, (__bf16)w3 };
            *(bf16x4*)&As[p][sr + e2 * 16][sk] = bv;
            rs[e2] += w0 + w1 + w2 + w3;
        }
        if (ch + 1 < c1) LOADC(ch + 1);        // issue next-chunk loads
        __syncthreads();                        // LDS[p] ready (1 barrier/chunk)
        #pragma unroll
        for (int kss = 0; kss < 2; ++kss) {
            bf16x8 a = *(const bf16x8*)&As[p][w * 16 + lr][kss * 32 + lk * 8];
            #pragma unroll
            for (int n = 0; n < 4; ++n) {
                bf16x8 b = *(const bf16x8*)&Bs[p][n * 16 + lr][kss * 32 + lk * 8];
                acc[n] = __builtin_amdgcn_mfma_f32_16x16x32_bf16(a, b, acc[n], 0, 0, 0);
            }
        }
        p ^= 1;
    }
#undef LOADC

    // row-sum partials: reduce across the 16 lanes sharing a row, plain store
    #pragma unroll
    for (int e = 0; e < 4; ++e) {
        float pp = rs[e];
        pp += __shfl_xor(pp, 1, 64);
        pp += __shfl_xor(pp, 2, 64);
        pp += __shfl_xor(pp, 4, 64);
        pp += __shfl_xor(pp, 8, 64);
        int r = e * 16 + sr;
        if ((t & 15) == 0 && row0 + r < NN)
            Sp[(size_t)ks * NN + row0 + r] = pp;
    }
    // C/D layout: col = lane&15, row = (lane>>4)*4 + reg ; plain stores
    #pragma unroll
    for (int n = 0; n < 4; ++n) {
        #pragma unroll
        for (int r = 0; r < 4; ++r) {
            int grow = row0 + w * 16 + lk * 4 + r;
            if (grow < NN)
                Nump[(size_t)ks * NN * FOUT + (size_t)grow * FOUT + n * 16 + lr]
                    = acc[n][r];
        }
    }
}

// ------- scatB: winner check + dw compute + push (j,dw) into row bucket -----
__global__ __launch_bounds__(256) void k_scatB(const int* __restrict__ ep,
                                               const float* __restrict__ sums,
                                               const float* __restrict__ cnts,
                                               const unsigned* __restrict__ hkey,
                                               const unsigned* __restrict__ hprio,
                                               const float* __restrict__ adj,
                                               int* __restrict__ rowcnt,
                                               uint2* __restrict__ pairs) {
    int e = blockIdx.x * 256 + threadIdx.x;
    if (e >= 2 * EE) return;
    int i, j, k;
    entry_ij(ep, e, i, j, k);
    unsigned cell = (unsigned)i * NN + (unsigned)j;
    unsigned keyv = cell + 1u;
    unsigned h = hash_cell(cell);
    while (hkey[h] != keyv) h = (h + 1u) & HMASK;
    if (hprio[h] == (unsigned)(e + 1)) {   // last-write-wins winner
        float v   = sums[k] / fmaxf(cnts[k], 1.0f);
        float sg  = 1.f / (1.f + __expf(-v));
        float aij = adj[(size_t)i * NN + j];
        float dw  = __expf(aij + sg) - __expf(aij + 0.5f);
        if (dw != 0.f) {
            int pos = atomicAdd(&rowcnt[i], 1);
            if (pos < ROWCAP)
                pairs[(size_t)i * ROWCAP + pos] =
                    make_uint2((unsigned)j, __float_as_uint(dw));
        }
    }
}

// ------- rowupd: one wave per row: sum partials + edge corr + elu -> out ----
__global__ __launch_bounds__(256) void k_rowupd(const float* __restrict__ Nump,
                                                const float* __restrict__ Sp,
                                                const int* __restrict__ rowcnt,
                                                const uint2* __restrict__ pairs,
                                                const float* __restrict__ seq,
                                                const float* __restrict__ bias,
                                                float* __restrict__ out) {
    int t = threadIdx.x;
    int i = blockIdx.x * 4 + (t >> 6);
    if (i >= NN) return;
    int c = t & 63;
    float acc = 0.f, sb = 0.f;
    #pragma unroll
    for (int ks = 0; ks < 8; ++ks) {
        acc += Nump[(size_t)ks * NN * FOUT + (size_t)i * FOUT + c];
        sb  += Sp[(size_t)ks * NN + i];
    }
    int cnt = min(rowcnt[i], ROWCAP);
    float sdw = 0.f;
    const uint2* pr = pairs + (size_t)i * ROWCAP;
    #pragma unroll 4
    for (int e = 0; e < cnt; ++e) {
        uint2 pk = pr[e];                      // wave-uniform broadcast load
        float d  = __uint_as_float(pk.y);
        acc += d * seq[(size_t)pk.x * FOUT + c];
        sdw += d;
    }
    float v = acc / (sb + sdw) + bias[c];
    out[(size_t)i * FOUT + c] = (v > 0.f) ? v : expm1f(v);
}

extern "C" void kernel_launch(void* const* d_in, const int* in_sizes, int n_in,
                              void* d_out, int out_size, void* d_ws, size_t ws_size,
                              hipStream_t stream) {
    const float* x    = (const float*)d_in[0];
    const float* rel  = (const float*)d_in[1];
    const float* adj  = (const float*)d_in[2];
    const int*   ep   = (const int*)d_in[3];
    const int*   rseg = (const int*)d_in[4];
    const float* W    = (const float*)d_in[5];
    const float* wrel = (const float*)d_in[6];
    const float* bias = (const float*)d_in[7];
    float* out = (float*)d_out;

    float* ws = (float*)d_ws;
    float*    sums   = ws + O_SUMS;
    float*    cnts   = ws + O_CNTS;
    int*      rowcnt = (int*)(ws + O_ROWCNT);
    unsigned* hkey   = (unsigned*)(ws + O_HKEY);
    unsigned* hprio  = (unsigned*)(ws + O_HPRIO);
    __bf16*   seqT   = (__bf16*)(ws + O_SEQT);
    float*    seq    = ws + O_SEQ;
    float*    Nump   = ws + O_NUMP;
    float*    Sp     = ws + O_SP;
    uint2*    pairs  = (uint2*)(ws + O_PAIRS);

    int n4 = ZERO_WORDS / 4;
    k_zero<<<(n4 + 255) / 256, 256, 0, stream>>>((f32x4*)d_ws, n4);
    k_seqfts<<<NN / 16, 256, 0, stream>>>(x, W, seq, seqT);
    k_mainrel<<<GRID_MR, 256, 0, stream>>>(adj, seqT, rel, wrel, rseg, ep,
                                           sums, cnts, hkey, hprio, Nump, Sp);
    k_scatB<<<SCATAB, 256, 0, stream>>>(ep, sums, cnts, hkey, hprio, adj,
                                        rowcnt, pairs);
    k_rowupd<<<(NN + 3) / 4, 256, 0, stream>>>(Nump, Sp, rowcnt, pairs,
                                               seq, bias, out);
}